// Round 7
// baseline (674.990 us; speedup 1.0000x reference)
//
#include <hip/hip_runtime.h>
#include <hip/hip_bf16.h>
#include <type_traits>

typedef __bf16 bf16_t;
typedef __bf16 bf16x8 __attribute__((ext_vector_type(8)));
typedef float floatx4 __attribute__((ext_vector_type(4)));
typedef short v2s __attribute__((ext_vector_type(2)));

#define NN 50000
#define EE 800000
#define DD 128

// ---- ws layout (bytes) ----
#define W1T_OFF   256
#define W2T_OFF   (W1T_OFF + (size_t)128 * 288 * 2)
#define NW1T_OFF  (W2T_OFF + (size_t)128 * 128 * 2)
#define NW2T_OFF  (NW1T_OFF + (size_t)128 * 256 * 2)
#define BIASF_OFF (NW2T_OFF + (size_t)128 * 128 * 2)
#define XB_OFF    207360
#define AGG_OFF   (XB_OFF + (size_t)NN * DD * 2)
#define AGG_BYTES ((size_t)NN * DD * 2)
#define WS_V2     (AGG_OFF + AGG_BYTES)                // 25.8 MB
#define P_OFF     WS_V2
#define Q_OFF     (P_OFF + (size_t)NN * DD * 2)
#define WS_V3     (Q_OFF + (size_t)NN * DD * 2)        // 51.4 MB (proven available)
#define HIST_OFF  WS_V3
#define OFFS_OFF  (HIST_OFF + 200192)
#define PERM_OFF  (OFFS_OFF + 200192)
#define WS_V4     (PERM_OFF + (size_t)EE * 4)          // 55.0 MB

// LDS pitches
#define PA 304
#define PB 48
#define PN 272
#define PH 136

// ---- dtype-detect ----
__global__ void detect_kernel(const unsigned short* __restrict__ xraw,
                              const unsigned int* __restrict__ eiraw,
                              int* __restrict__ flags)
{
    int cnt = 0;
    for (int i = 0; i < 64; ++i) {
        unsigned short u = xraw[2 * i];
        int ex = (u >> 7) & 0xFF;
        if (ex >= 100 && ex <= 140) cnt++;
    }
    flags[0] = (cnt < 32) ? 1 : 0;   // 1 => fp32
    int zc = 0;
    for (int i = 0; i < 32; ++i)
        if (eiraw[2 * i + 1] == 0u) zc++;
    flags[1] = (zc >= 16) ? 1 : 0;   // 1 => int64
}

__device__ inline int load_idx(const void* ei, int i64, size_t pos)
{
    return i64 ? (int)((const long long*)ei)[pos] : ((const int*)ei)[pos];
}

template <typename FT>
__device__ __forceinline__ void cp8(bf16_t* dst, const FT* src)
{
    if constexpr (std::is_same<FT, float>::value) {
#pragma unroll
        for (int i = 0; i < 8; i += 4) {
            float4 v = *(const float4*)(src + i);
            dst[i + 0] = (bf16_t)v.x; dst[i + 1] = (bf16_t)v.y;
            dst[i + 2] = (bf16_t)v.z; dst[i + 3] = (bf16_t)v.w;
        }
    } else {
        *(bf16x8*)dst = *(const bf16x8*)src;
    }
}

__device__ inline void pk_atomic_add_bf16(bf16_t* addr, float lo, float hi)
{
#if __has_builtin(__builtin_amdgcn_global_atomic_fadd_v2bf16)
    union { bf16_t b[2]; v2s s; } pk;
    pk.b[0] = (bf16_t)lo;
    pk.b[1] = (bf16_t)hi;
    (void)__builtin_amdgcn_global_atomic_fadd_v2bf16((v2s*)addr, pk.s);
#else
    unsigned int* w = (unsigned int*)addr;
    unsigned int old = __hip_atomic_load(w, __ATOMIC_RELAXED, __HIP_MEMORY_SCOPE_AGENT);
    while (true) {
        union { unsigned int u; bf16_t b[2]; } cur;
        cur.u = old;
        cur.b[0] = (bf16_t)((float)cur.b[0] + lo);
        cur.b[1] = (bf16_t)((float)cur.b[1] + hi);
        unsigned int prev = atomicCAS(w, old, cur.u);
        if (prev == old) break;
        old = prev;
    }
#endif
}

// ---- prep (runtime-switched): transpose weights -> bf16 ws; biases -> float ----
template <typename FT>
__device__ __forceinline__ void prep_impl(
    const FT* eW1, const FT* eW2, const FT* nW1, const FT* nW2,
    const FT* b1, const FT* b2, const FT* nb1, const FT* nb2,
    bf16_t* W1t, bf16_t* W2t, bf16_t* nW1t, bf16_t* nW2t, float* biasF, int idx)
{
    if (idx < 128 * 288) {
        int n = idx / 288;
        int k = idx - n * 288;
        W1t[idx] = (k < 272) ? (bf16_t)(float)eW1[k * 128 + n] : (bf16_t)0.0f;
    } else if (idx < 128 * 288 + 128 * 128) {
        int j = idx - 128 * 288;
        int n = j >> 7, k = j & 127;
        W2t[j] = (bf16_t)(float)eW2[k * 128 + n];
    } else if (idx < 128 * 288 + 128 * 128 + 128 * 256) {
        int j = idx - (128 * 288 + 128 * 128);
        int n = j >> 8, k = j & 255;
        nW1t[j] = (bf16_t)(float)nW1[k * 128 + n];
    } else if (idx < 102400) {
        int j = idx - (128 * 288 + 128 * 128 + 128 * 256);
        int n = j >> 7, k = j & 127;
        nW2t[j] = (bf16_t)(float)nW2[k * 128 + n];
    } else if (idx < 102912) {
        int j = idx - 102400;
        int which = j >> 7, c = j & 127;
        const FT* src = which == 0 ? b1 : which == 1 ? b2 : which == 2 ? nb1 : nb2;
        biasF[j] = (float)src[c];
    }
}

__global__ __launch_bounds__(256) void prep_kernel(
    const void* eW1, const void* eW2, const void* nW1, const void* nW2,
    const void* b1, const void* b2, const void* nb1, const void* nb2,
    bf16_t* W1t, bf16_t* W2t, bf16_t* nW1t, bf16_t* nW2t,
    float* biasF, const int* flags)
{
    int idx = blockIdx.x * 256 + threadIdx.x;
    if (flags[0])
        prep_impl<float>((const float*)eW1, (const float*)eW2, (const float*)nW1,
                         (const float*)nW2, (const float*)b1, (const float*)b2,
                         (const float*)nb1, (const float*)nb2,
                         W1t, W2t, nW1t, nW2t, biasF, idx);
    else
        prep_impl<bf16_t>((const bf16_t*)eW1, (const bf16_t*)eW2, (const bf16_t*)nW1,
                          (const bf16_t*)nW2, (const bf16_t*)b1, (const bf16_t*)b2,
                          (const bf16_t*)nb1, (const bf16_t*)nb2,
                          W1t, W2t, nW1t, nW2t, biasF, idx);
}

// ---- conv_x (runtime-switched) ----
__global__ __launch_bounds__(256) void conv_x_kernel(
    const void* x, bf16_t* __restrict__ xb, const int* __restrict__ flags)
{
    size_t i = ((size_t)blockIdx.x * 256 + threadIdx.x) * 8;
    if (i >= (size_t)NN * DD) return;
    bf16x8 v;
    if (flags[0]) {
        const float* xf = (const float*)x;
        float4 a = *(const float4*)(xf + i);
        float4 b = *(const float4*)(xf + i + 4);
        v[0] = (bf16_t)a.x; v[1] = (bf16_t)a.y; v[2] = (bf16_t)a.z; v[3] = (bf16_t)a.w;
        v[4] = (bf16_t)b.x; v[5] = (bf16_t)b.y; v[6] = (bf16_t)b.z; v[7] = (bf16_t)b.w;
    } else {
        v = *(const bf16x8*)((const bf16_t*)x + i);
    }
    *(bf16x8*)(xb + i) = v;
}

// ---- pq: P = xb @ eW1[0:128], Q = xb @ eW1[128:256] ----
__global__ __launch_bounds__(256) void pq_kernel(
    const bf16_t* __restrict__ xb, const bf16_t* __restrict__ W1t,
    bf16_t* __restrict__ P, bf16_t* __restrict__ Q)
{
    __shared__ bf16_t sX[64 * PH];
    __shared__ bf16_t sB[128 * PB];
    const int tid = threadIdx.x;
    const int n0 = blockIdx.x * 64;

    {
        const int m = tid >> 2;
        const int part = tid & 3;
        int n = n0 + m;
        if (n >= NN) n = NN - 1;
        const bf16x8* src = (const bf16x8*)(xb + (size_t)n * DD + part * 32);
        bf16x8* dst = (bf16x8*)&sX[m * PH + part * 32];
#pragma unroll
        for (int i = 0; i < 4; ++i) dst[i] = src[i];
    }

    const int lane = tid & 63;
    const int wv = tid >> 6;
    const int ml = lane & 15;
    const int q = lane >> 4;
    const int m0 = wv * 16;
    const floatx4 fzero = {0.f, 0.f, 0.f, 0.f};

    for (int pass = 0; pass < 2; ++pass) {
        floatx4 acc[8];
#pragma unroll
        for (int i = 0; i < 8; ++i) acc[i] = fzero;

        for (int kc = 0; kc < 4; ++kc) {
            __syncthreads();
            {
                const int n = tid >> 1;
                const int half = tid & 1;
                const bf16x8* src = (const bf16x8*)(W1t + n * 288 + pass * 128 + kc * 32 + half * 16);
                bf16x8* dst = (bf16x8*)&sB[n * PB + half * 16];
                dst[0] = src[0];
                dst[1] = src[1];
            }
            __syncthreads();
            const bf16x8 a = *(const bf16x8*)&sX[(m0 + ml) * PH + kc * 32 + q * 8];
#pragma unroll
            for (int nt = 0; nt < 8; ++nt) {
                const bf16x8 b = *(const bf16x8*)&sB[(nt * 16 + ml) * PB + q * 8];
                acc[nt] = __builtin_amdgcn_mfma_f32_16x16x32_bf16(a, b, acc[nt], 0, 0, 0);
            }
        }

        bf16_t* dst = pass ? Q : P;
#pragma unroll
        for (int r = 0; r < 4; ++r) {
            const int n = n0 + m0 + q * 4 + r;
#pragma unroll
            for (int nt = 0; nt < 8; ++nt) {
                float v = acc[nt][r];
                const float pv = __shfl_xor(v, 1, 64);
                if (((lane & 1) == 0) && n < NN) {
                    union { bf16_t b[2]; unsigned int u; } pk;
                    pk.b[0] = (bf16_t)v;
                    pk.b[1] = (bf16_t)pv;
                    *(unsigned int*)(dst + (size_t)n * DD + nt * 16 + ml) = pk.u;
                }
            }
        }
    }
}

// ---- counting sort of edges by destination row ----
__global__ __launch_bounds__(256) void hist_kernel(
    const void* __restrict__ ei, unsigned* __restrict__ hist,
    const int* __restrict__ flags)
{
    const int i64 = flags[1];
    int e = blockIdx.x * 256 + threadIdx.x;
    if (e >= EE) return;
    int rn = load_idx(ei, i64, e);
    rn = min(max(rn, 0), NN - 1);
    atomicAdd(&hist[rn], 1u);
}

__global__ __launch_bounds__(1024) void scan_kernel(
    const unsigned* __restrict__ hist, unsigned* __restrict__ offs)
{
    __shared__ unsigned sp[1024];
    const int t = threadIdx.x;
    const int base = t * 49;
    unsigned sum = 0;
    for (int i = 0; i < 49; ++i) {
        int idx = base + i;
        if (idx < NN) sum += hist[idx];
    }
    sp[t] = sum;
    __syncthreads();
    for (int off = 1; off < 1024; off <<= 1) {
        unsigned v = 0;
        if (t >= off) v = sp[t - off];
        __syncthreads();
        sp[t] += v;
        __syncthreads();
    }
    unsigned run = sp[t] - sum;   // exclusive
    for (int i = 0; i < 49; ++i) {
        int idx = base + i;
        if (idx < NN) {
            offs[idx] = run;
            run += hist[idx];
        }
    }
}

__global__ __launch_bounds__(256) void scatter_ids_kernel(
    const void* __restrict__ ei, unsigned* __restrict__ offs,
    unsigned* __restrict__ perm, const int* __restrict__ flags)
{
    const int i64 = flags[1];
    int e = blockIdx.x * 256 + threadIdx.x;
    if (e >= EE) return;
    int rn = load_idx(ei, i64, e);
    rn = min(max(rn, 0), NN - 1);
    unsigned pos = atomicAdd(&offs[rn], 1u);
    perm[pos] = (unsigned)e;
}

// ======== edge v4: sorted edges, run-dedup scatter ========
__global__ __launch_bounds__(256) void edge_kernel_v4(
    const void* __restrict__ ei, const void* __restrict__ ea,
    const unsigned* __restrict__ perm,
    const bf16_t* __restrict__ P, const bf16_t* __restrict__ Q,
    const bf16_t* __restrict__ W1t, const bf16_t* __restrict__ W2t,
    const float* __restrict__ biasF,
    bf16_t* __restrict__ agg, const int* __restrict__ flags)
{
    const int f32 = flags[0];
    const int i64 = flags[1];

    __shared__ bf16_t sH[64 * PH];
    __shared__ bf16_t sEA[64 * 32];
    __shared__ bf16_t sB[128 * PB];
    __shared__ int sR[64];
    const int tid = threadIdx.x;
    const int e0 = blockIdx.x * 64;

    // ---- stage: sH = bf16(P[rn]+Q[cn]); sEA; sB = ea-chunk of W1t; sR = rows ----
    {
        const int m = tid >> 2;
        const int part = tid & 3;
        const int e = (int)perm[e0 + m];
        int rn = load_idx(ei, i64, e);
        int cn = load_idx(ei, i64, (size_t)EE + e);
        rn = min(max(rn, 0), NN - 1);
        cn = min(max(cn, 0), NN - 1);
        if (part == 0) sR[m] = rn;
        const bf16x8* pr = (const bf16x8*)(P + (size_t)rn * DD + part * 32);
        const bf16x8* qc = (const bf16x8*)(Q + (size_t)cn * DD + part * 32);
#pragma unroll
        for (int i = 0; i < 4; ++i) {
            bf16x8 a = pr[i], b = qc[i], o;
#pragma unroll
            for (int j = 0; j < 8; ++j) o[j] = (bf16_t)((float)a[j] + (float)b[j]);
            *(bf16x8*)&sH[m * PH + part * 32 + i * 8] = o;
        }
        if (part < 2) {
            if (f32) cp8<float>(&sEA[m * 32 + part * 8], (const float*)ea + (size_t)e * 16 + part * 8);
            else     cp8<bf16_t>(&sEA[m * 32 + part * 8], (const bf16_t*)ea + (size_t)e * 16 + part * 8);
        } else {
            *(float4*)&sEA[m * 32 + part * 8] = make_float4(0.f, 0.f, 0.f, 0.f);
        }
        {
            const int n = tid >> 1;
            const int half = tid & 1;
            const bf16x8* src = (const bf16x8*)(W1t + n * 288 + 256 + half * 16);
            bf16x8* dst = (bf16x8*)&sB[n * PB + half * 16];
            dst[0] = src[0];
            dst[1] = src[1];
        }
    }
    __syncthreads();

    const int lane = tid & 63;
    const int wv = tid >> 6;
    const int ml = lane & 15;
    const int q = lane >> 4;
    const int m0 = wv * 16;
    const floatx4 fzero = {0.f, 0.f, 0.f, 0.f};

    // ---- ea contribution ----
    floatx4 acc[8];
#pragma unroll
    for (int i = 0; i < 8; ++i) acc[i] = fzero;
    {
        const bf16x8 a = *(const bf16x8*)&sEA[(m0 + ml) * 32 + q * 8];
#pragma unroll
        for (int nt = 0; nt < 8; ++nt) {
            const bf16x8 b = *(const bf16x8*)&sB[(nt * 16 + ml) * PB + q * 8];
            acc[nt] = __builtin_amdgcn_mfma_f32_16x16x32_bf16(a, b, acc[nt], 0, 0, 0);
        }
    }

    // ---- h = silu(acc + (P+Q) + b1) ----
#pragma unroll
    for (int nt = 0; nt < 8; ++nt) {
        const float bias = biasF[nt * 16 + ml];
#pragma unroll
        for (int r = 0; r < 4; ++r) {
            const int row = m0 + q * 4 + r;
            const int col = nt * 16 + ml;
            float v = acc[nt][r] + bias + (float)sH[row * PH + col];
            v = v / (1.f + __expf(-v));
            sH[row * PH + col] = (bf16_t)v;
        }
    }

    floatx4 acc2[8];
#pragma unroll
    for (int i = 0; i < 8; ++i) acc2[i] = fzero;

    // ---- layer 2 ----
    for (int kc = 0; kc < 4; ++kc) {
        __syncthreads();
        {
            const int n = tid >> 1;
            const int half = tid & 1;
            const bf16x8* src = (const bf16x8*)(W2t + n * 128 + kc * 32 + half * 16);
            bf16x8* dst = (bf16x8*)&sB[n * PB + half * 16];
            dst[0] = src[0];
            dst[1] = src[1];
        }
        __syncthreads();
        const bf16x8 a = *(const bf16x8*)&sH[(m0 + ml) * PH + kc * 32 + q * 8];
#pragma unroll
        for (int nt = 0; nt < 8; ++nt) {
            const bf16x8 b = *(const bf16x8*)&sB[(nt * 16 + ml) * PB + q * 8];
            acc2[nt] = __builtin_amdgcn_mfma_f32_16x16x32_bf16(a, b, acc2[nt], 0, 0, 0);
        }
    }

    // ---- scatter with run dedup (rows sorted => runs within the 4-edge window) ----
    const int w0 = sR[m0 + q * 4 + 0];
    const int w1 = sR[m0 + q * 4 + 1];
    const int w2 = sR[m0 + q * 4 + 2];
    const int w3 = sR[m0 + q * 4 + 3];
#pragma unroll
    for (int nt = 0; nt < 8; ++nt) {
        const float bias = biasF[128 + nt * 16 + ml];
        float v0 = acc2[nt][0] + bias; v0 = v0 / (1.f + __expf(-v0));
        float v1 = acc2[nt][1] + bias; v1 = v1 / (1.f + __expf(-v1));
        float v2 = acc2[nt][2] + bias; v2 = v2 / (1.f + __expf(-v2));
        float v3 = acc2[nt][3] + bias; v3 = v3 / (1.f + __expf(-v3));
        const float p0 = __shfl_xor(v0, 1, 64);
        const float p1 = __shfl_xor(v1, 1, 64);
        const float p2 = __shfl_xor(v2, 1, 64);
        const float p3 = __shfl_xor(v3, 1, 64);
        if ((ml & 1) == 0) {
            bf16_t* const col = agg + nt * 16 + ml;
            int row = w0; float lo = v0, hi = p0;
            if (w1 == row) { lo += v1; hi += p1; }
            else { pk_atomic_add_bf16(col + (size_t)row * DD, lo, hi); row = w1; lo = v1; hi = p1; }
            if (w2 == row) { lo += v2; hi += p2; }
            else { pk_atomic_add_bf16(col + (size_t)row * DD, lo, hi); row = w2; lo = v2; hi = p2; }
            if (w3 == row) { lo += v3; hi += p3; }
            else { pk_atomic_add_bf16(col + (size_t)row * DD, lo, hi); row = w3; lo = v3; hi = p3; }
            pk_atomic_add_bf16(col + (size_t)row * DD, lo, hi);
        }
    }
}

// ======== edge v3 (fallback, unsorted) ========
__global__ __launch_bounds__(256) void edge_kernel_v3(
    const void* __restrict__ ei, const void* __restrict__ ea,
    const bf16_t* __restrict__ P, const bf16_t* __restrict__ Q,
    const bf16_t* __restrict__ W1t, const bf16_t* __restrict__ W2t,
    const float* __restrict__ biasF,
    bf16_t* __restrict__ agg, const int* __restrict__ flags)
{
    const int f32 = flags[0];
    const int i64 = flags[1];

    __shared__ bf16_t sH[64 * PH];
    __shared__ bf16_t sEA[64 * 32];
    __shared__ bf16_t sB[128 * PB];
    const int tid = threadIdx.x;
    const int e0 = blockIdx.x * 64;

    {
        const int m = tid >> 2;
        const int part = tid & 3;
        const int e = e0 + m;
        int rn = load_idx(ei, i64, e);
        int cn = load_idx(ei, i64, (size_t)EE + e);
        rn = min(max(rn, 0), NN - 1);
        cn = min(max(cn, 0), NN - 1);
        const bf16x8* pr = (const bf16x8*)(P + (size_t)rn * DD + part * 32);
        const bf16x8* qc = (const bf16x8*)(Q + (size_t)cn * DD + part * 32);
#pragma unroll
        for (int i = 0; i < 4; ++i) {
            bf16x8 a = pr[i], b = qc[i], o;
#pragma unroll
            for (int j = 0; j < 8; ++j) o[j] = (bf16_t)((float)a[j] + (float)b[j]);
            *(bf16x8*)&sH[m * PH + part * 32 + i * 8] = o;
        }
        if (part < 2) {
            if (f32) cp8<float>(&sEA[m * 32 + part * 8], (const float*)ea + (size_t)e * 16 + part * 8);
            else     cp8<bf16_t>(&sEA[m * 32 + part * 8], (const bf16_t*)ea + (size_t)e * 16 + part * 8);
        } else {
            *(float4*)&sEA[m * 32 + part * 8] = make_float4(0.f, 0.f, 0.f, 0.f);
        }
        {
            const int n = tid >> 1;
            const int half = tid & 1;
            const bf16x8* src = (const bf16x8*)(W1t + n * 288 + 256 + half * 16);
            bf16x8* dst = (bf16x8*)&sB[n * PB + half * 16];
            dst[0] = src[0];
            dst[1] = src[1];
        }
    }
    __syncthreads();

    const int lane = tid & 63;
    const int wv = tid >> 6;
    const int ml = lane & 15;
    const int q = lane >> 4;
    const int m0 = wv * 16;
    const floatx4 fzero = {0.f, 0.f, 0.f, 0.f};

    floatx4 acc[8];
#pragma unroll
    for (int i = 0; i < 8; ++i) acc[i] = fzero;
    {
        const bf16x8 a = *(const bf16x8*)&sEA[(m0 + ml) * 32 + q * 8];
#pragma unroll
        for (int nt = 0; nt < 8; ++nt) {
            const bf16x8 b = *(const bf16x8*)&sB[(nt * 16 + ml) * PB + q * 8];
            acc[nt] = __builtin_amdgcn_mfma_f32_16x16x32_bf16(a, b, acc[nt], 0, 0, 0);
        }
    }

#pragma unroll
    for (int nt = 0; nt < 8; ++nt) {
        const float bias = biasF[nt * 16 + ml];
#pragma unroll
        for (int r = 0; r < 4; ++r) {
            const int row = m0 + q * 4 + r;
            const int col = nt * 16 + ml;
            float v = acc[nt][r] + bias + (float)sH[row * PH + col];
            v = v / (1.f + __expf(-v));
            sH[row * PH + col] = (bf16_t)v;
        }
    }

    floatx4 acc2[8];
#pragma unroll
    for (int i = 0; i < 8; ++i) acc2[i] = fzero;

    for (int kc = 0; kc < 4; ++kc) {
        __syncthreads();
        {
            const int n = tid >> 1;
            const int half = tid & 1;
            const bf16x8* src = (const bf16x8*)(W2t + n * 128 + kc * 32 + half * 16);
            bf16x8* dst = (bf16x8*)&sB[n * PB + half * 16];
            dst[0] = src[0];
            dst[1] = src[1];
        }
        __syncthreads();
        const bf16x8 a = *(const bf16x8*)&sH[(m0 + ml) * PH + kc * 32 + q * 8];
#pragma unroll
        for (int nt = 0; nt < 8; ++nt) {
            const bf16x8 b = *(const bf16x8*)&sB[(nt * 16 + ml) * PB + q * 8];
            acc2[nt] = __builtin_amdgcn_mfma_f32_16x16x32_bf16(a, b, acc2[nt], 0, 0, 0);
        }
    }

    float bias2[8];
#pragma unroll
    for (int nt = 0; nt < 8; ++nt) bias2[nt] = biasF[128 + nt * 16 + ml];
#pragma unroll
    for (int r = 0; r < 4; ++r) {
        const int e = e0 + m0 + q * 4 + r;
        int rn = load_idx(ei, i64, e);
        rn = min(max(rn, 0), NN - 1);
#pragma unroll
        for (int nt = 0; nt < 8; ++nt) {
            float v = acc2[nt][r] + bias2[nt];
            v = v / (1.f + __expf(-v));
            const float pv = __shfl_xor(v, 1, 64);
            if ((ml & 1) == 0)
                pk_atomic_add_bf16(agg + (size_t)rn * DD + nt * 16 + ml, v, pv);
        }
    }
}

// -------- node MLP (runtime-switched) --------
template <typename FT>
__device__ __forceinline__ void node_impl(
    const FT* x, const bf16_t* xb, const bf16_t* agg,
    const bf16_t* nW1t, const bf16_t* nW2t, const float* biasF,
    FT* out, bf16_t* sA, bf16_t* sB)
{
    const int tid = threadIdx.x;
    const int n0 = blockIdx.x * 64;

    {
        const int m = tid >> 2;
        const int p = tid & 3;
        int n = n0 + m;
        if (n >= NN) n = NN - 1;
        const bf16_t* srcbase = (p < 2) ? xb : agg;
        const int col = (p & 1) * 64;
        const bf16x8* src = (const bf16x8*)(srcbase + (size_t)n * DD + col);
        bf16x8* dst = (bf16x8*)&sA[m * PN + (p >> 1) * 128 + col];
#pragma unroll
        for (int i = 0; i < 8; ++i) dst[i] = src[i];
    }

    const int lane = tid & 63;
    const int wv = tid >> 6;
    const int ml = lane & 15;
    const int q = lane >> 4;
    const int m0 = wv * 16;

    const floatx4 fzero = {0.f, 0.f, 0.f, 0.f};
    floatx4 acc[8];
#pragma unroll
    for (int i = 0; i < 8; ++i) acc[i] = fzero;

    for (int kc = 0; kc < 8; ++kc) {
        __syncthreads();
        {
            const int n = tid >> 1;
            const int half = tid & 1;
            const bf16x8* src = (const bf16x8*)(nW1t + n * 256 + kc * 32 + half * 16);
            bf16x8* dst = (bf16x8*)&sB[n * PB + half * 16];
            dst[0] = src[0];
            dst[1] = src[1];
        }
        __syncthreads();
        const bf16x8 a = *(const bf16x8*)&sA[(m0 + ml) * PN + kc * 32 + q * 8];
#pragma unroll
        for (int nt = 0; nt < 8; ++nt) {
            const bf16x8 b = *(const bf16x8*)&sB[(nt * 16 + ml) * PB + q * 8];
            acc[nt] = __builtin_amdgcn_mfma_f32_16x16x32_bf16(a, b, acc[nt], 0, 0, 0);
        }
    }

#pragma unroll
    for (int nt = 0; nt < 8; ++nt) {
        const float bias = biasF[256 + nt * 16 + ml];
#pragma unroll
        for (int r = 0; r < 4; ++r) {
            float v = acc[nt][r] + bias;
            v = v / (1.f + __expf(-v));
            sA[(m0 + q * 4 + r) * PN + nt * 16 + ml] = (bf16_t)v;
        }
    }
    __syncthreads();

    floatx4 acc2[8];
#pragma unroll
    for (int i = 0; i < 8; ++i) acc2[i] = fzero;

    for (int kc = 0; kc < 4; ++kc) {
        __syncthreads();
        {
            const int n = tid >> 1;
            const int half = tid & 1;
            const bf16x8* src = (const bf16x8*)(nW2t + n * 128 + kc * 32 + half * 16);
            bf16x8* dst = (bf16x8*)&sB[n * PB + half * 16];
            dst[0] = src[0];
            dst[1] = src[1];
        }
        __syncthreads();
        const bf16x8 a = *(const bf16x8*)&sA[(m0 + ml) * PN + kc * 32 + q * 8];
#pragma unroll
        for (int nt = 0; nt < 8; ++nt) {
            const bf16x8 b = *(const bf16x8*)&sB[(nt * 16 + ml) * PB + q * 8];
            acc2[nt] = __builtin_amdgcn_mfma_f32_16x16x32_bf16(a, b, acc2[nt], 0, 0, 0);
        }
    }

#pragma unroll
    for (int r = 0; r < 4; ++r) {
        const int n = n0 + m0 + q * 4 + r;
        if (n < NN) {
#pragma unroll
            for (int nt = 0; nt < 8; ++nt) {
                const int col = nt * 16 + ml;
                float v = acc2[nt][r] + biasF[384 + col];
                float xv = (float)x[(size_t)n * DD + col];
                out[(size_t)n * DD + col] = (FT)(xv + v);
            }
        }
    }
}

__global__ __launch_bounds__(256) void node_kernel(
    const void* x, const bf16_t* __restrict__ xb, const bf16_t* __restrict__ agg,
    const bf16_t* __restrict__ nW1t, const bf16_t* __restrict__ nW2t,
    const float* __restrict__ biasF, void* out, const int* __restrict__ flags)
{
    __shared__ bf16_t sA[64 * PN];
    __shared__ bf16_t sB[128 * PB];
    if (flags[0])
        node_impl<float>((const float*)x, xb, agg, nW1t, nW2t, biasF, (float*)out, sA, sB);
    else
        node_impl<bf16_t>((const bf16_t*)x, xb, agg, nW1t, nW2t, biasF, (bf16_t*)out, sA, sB);
}

extern "C" void kernel_launch(void* const* d_in, const int* in_sizes, int n_in,
                              void* d_out, int out_size, void* d_ws, size_t ws_size,
                              hipStream_t stream)
{
    const void* x   = d_in[0];
    const void* ei  = d_in[1];
    const void* ea  = d_in[2];
    const void* eW1 = d_in[3];
    const void* eb1 = d_in[4];
    const void* eW2 = d_in[5];
    const void* eb2 = d_in[6];
    const void* nW1 = d_in[7];
    const void* nb1 = d_in[8];
    const void* nW2 = d_in[9];
    const void* nb2 = d_in[10];

    char* ws = (char*)d_ws;
    int*      flags = (int*)ws;
    bf16_t*   W1t   = (bf16_t*)(ws + W1T_OFF);
    bf16_t*   W2t   = (bf16_t*)(ws + W2T_OFF);
    bf16_t*   nW1t  = (bf16_t*)(ws + NW1T_OFF);
    bf16_t*   nW2t  = (bf16_t*)(ws + NW2T_OFF);
    float*    biasF = (float*)(ws + BIASF_OFF);
    bf16_t*   xb    = (bf16_t*)(ws + XB_OFF);
    bf16_t*   agg   = (bf16_t*)(ws + AGG_OFF);
    bf16_t*   P     = (bf16_t*)(ws + P_OFF);
    bf16_t*   Q     = (bf16_t*)(ws + Q_OFF);
    unsigned* hist  = (unsigned*)(ws + HIST_OFF);
    unsigned* offs  = (unsigned*)(ws + OFFS_OFF);
    unsigned* perm  = (unsigned*)(ws + PERM_OFF);

    detect_kernel<<<1, 1, 0, stream>>>((const unsigned short*)x,
                                       (const unsigned int*)ei, flags);

    prep_kernel<<<403, 256, 0, stream>>>(eW1, eW2, nW1, nW2, eb1, eb2, nb1, nb2,
                                         W1t, W2t, nW1t, nW2t, biasF, flags);

    (void)hipMemsetAsync(agg, 0, AGG_BYTES, stream);
    conv_x_kernel<<<3125, 256, 0, stream>>>(x, xb, flags);

    if (ws_size >= WS_V4) {
        (void)hipMemsetAsync(hist, 0, NN * sizeof(unsigned), stream);
        hist_kernel<<<(EE + 255) / 256, 256, 0, stream>>>(ei, hist, flags);
        scan_kernel<<<1, 1024, 0, stream>>>(hist, offs);
        scatter_ids_kernel<<<(EE + 255) / 256, 256, 0, stream>>>(ei, offs, perm, flags);
        pq_kernel<<<(NN + 63) / 64, 256, 0, stream>>>(xb, W1t, P, Q);
        edge_kernel_v4<<<EE / 64, 256, 0, stream>>>(ei, ea, perm, P, Q, W1t, W2t,
                                                    biasF, agg, flags);
    } else if (ws_size >= WS_V3) {
        pq_kernel<<<(NN + 63) / 64, 256, 0, stream>>>(xb, W1t, P, Q);
        edge_kernel_v3<<<EE / 64, 256, 0, stream>>>(ei, ea, P, Q, W1t, W2t,
                                                    biasF, agg, flags);
    }

    node_kernel<<<(NN + 63) / 64, 256, 0, stream>>>(x, xb, agg, nW1t, nW2t, biasF,
                                                    d_out, flags);
}